// Round 3
// baseline (776.097 us; speedup 1.0000x reference)
//
#include <hip/hip_runtime.h>

#define HH 1024
#define WW 1024
#define RPT 8            // output rows per thread
#define NR (RPT + 10)    // input rows streamed per wave
#define WAVES 4
#define ROWF 272         // floats per staged row window (68 chunks of 4)

__global__ __launch_bounds__(256) void diamond_kernel(const float* __restrict__ in,
                                                      float* __restrict__ out) {
    __shared__ __attribute__((aligned(16))) float lds[WAVES][2][ROWF];

    const int tj = threadIdx.x;          // lane 0..63
    const int ty = threadIdx.y;          // wave 0..3
    const int b  = blockIdx.z;
    const int J0 = blockIdx.x * 256;                      // wave's first output col
    const int i0 = blockIdx.y * (WAVES * RPT) + ty * RPT; // wave's first output row
    const float* __restrict__ src = in  + (size_t)b * HH * WW;
    float*       __restrict__ dst = out + (size_t)b * HH * WW;

    const float EV[6] = {1.0f,
                         0.36787944117144233f,   // e^-1
                         0.1353352832366127f,    // e^-2
                         0.049787068367863944f,  // e^-3
                         0.018315638888734179f,  // e^-4
                         0.006737946999085467f}; // e^-5

    float acc[RPT][4];
#pragma unroll
    for (int m = 0; m < RPT; ++m)
#pragma unroll
        for (int p = 0; p < 4; ++p) acc[m][p] = 0.0f;

    const int cb_own  = (J0 - 8 + 4 * tj) & (WW - 1);
    const int cb_halo = (J0 - 8 + 4 * (64 + tj)) & (WW - 1);  // only tj<4
    const bool halo = (tj < 4);
    float* const w0 = &lds[ty][0][0];
    float* const w1 = &lds[ty][1][0];

    // compile-time-indexed only (full unroll) => stays in registers
    float4 c[NR], h[NR];

    const float* rp;
#define ROWP(rr) (src + (size_t)((i0 + (rr) - 5) & (HH - 1)) * WW)

    // ---- prologue: row 0 staged; rows 1,2 in flight ----
    rp = ROWP(0);
    c[0] = *reinterpret_cast<const float4*>(rp + cb_own);
    if (halo) h[0] = *reinterpret_cast<const float4*>(rp + cb_halo);
    *reinterpret_cast<float4*>(w0 + 4 * tj) = c[0];
    if (halo) *reinterpret_cast<float4*>(w0 + 256 + 4 * tj) = h[0];
    rp = ROWP(1);
    c[1] = *reinterpret_cast<const float4*>(rp + cb_own);
    if (halo) h[1] = *reinterpret_cast<const float4*>(rp + cb_halo);
    rp = ROWP(2);
    c[2] = *reinterpret_cast<const float4*>(rp + cb_own);
    if (halo) h[2] = *reinterpret_cast<const float4*>(rp + cb_halo);

#pragma unroll
    for (int rr = 0; rr < NR; ++rr) {
        // makes prev iter's LDS writes visible; drains vmem (so prefetch is
        // issued AFTER the barrier, giving it a full iteration of overlap)
        __syncthreads();

        if (rr + 3 < NR) {
            rp = ROWP(rr + 3);
            c[rr + 3] = *reinterpret_cast<const float4*>(rp + cb_own);
            if (halo) h[rr + 3] = *reinterpret_cast<const float4*>(rp + cb_halo);
        }

        float* const bufc = (rr & 1) ? w1 : w0;
        float* const bufn = (rr & 1) ? w0 : w1;

        // gather 20-float window: s[0..3] from register, s[4..19] from LDS
        float s[20];
        s[0] = c[rr].x; s[1] = c[rr].y; s[2] = c[rr].z; s[3] = c[rr].w;
#pragma unroll
        for (int t = 1; t < 5; ++t) {
            float4 v = *reinterpret_cast<const float4*>(bufc + 4 * tj + 4 * t);
            s[4 * t + 0] = v.x; s[4 * t + 1] = v.y;
            s[4 * t + 2] = v.z; s[4 * t + 3] = v.w;
        }

        // horizontal level-k sums consumed on the fly:
        // level k feeds output rows m = rr-k and m = rr-10+k with weight EV[5-k]
        float Hc[4];
#pragma unroll
        for (int p = 0; p < 4; ++p) Hc[p] = s[8 + p];
        {   // k = 0, a = 5
            const int m1 = rr - 10, m2 = rr;
            if (m1 >= 0 && m1 < RPT)
#pragma unroll
                for (int p = 0; p < 4; ++p) acc[m1][p] = fmaf(EV[5], Hc[p], acc[m1][p]);
            if (m2 >= 0 && m2 < RPT)
#pragma unroll
                for (int p = 0; p < 4; ++p) acc[m2][p] = fmaf(EV[5], Hc[p], acc[m2][p]);
        }
#pragma unroll
        for (int k = 1; k <= 4; ++k) {
#pragma unroll
            for (int p = 0; p < 4; ++p)
                Hc[p] = fmaf(EV[k], s[8 + p - k] + s[8 + p + k], Hc[p]);
            const int a = 5 - k;
            const int m1 = rr - 10 + k, m2 = rr - k;
            if (m1 >= 0 && m1 < RPT)
#pragma unroll
                for (int p = 0; p < 4; ++p) acc[m1][p] = fmaf(EV[a], Hc[p], acc[m1][p]);
            if (m2 >= 0 && m2 < RPT && m2 != m1)
#pragma unroll
                for (int p = 0; p < 4; ++p) acc[m2][p] = fmaf(EV[a], Hc[p], acc[m2][p]);
        }
        {   // k = 5 → center row (a = 0): weight 1, subtract the self term
#pragma unroll
            for (int p = 0; p < 4; ++p)
                Hc[p] = fmaf(EV[5], s[8 + p - 5] + s[8 + p + 5], Hc[p]);
            const int m = rr - 5;
            if (m >= 0 && m < RPT)
#pragma unroll
                for (int p = 0; p < 4; ++p) acc[m][p] += Hc[p] - s[8 + p];
        }

        // stage row rr+1 into the other buffer (visible after next barrier)
        if (rr + 1 < NR) {
            *reinterpret_cast<float4*>(bufn + 4 * tj) = c[rr + 1];
            if (halo) *reinterpret_cast<float4*>(bufn + 256 + 4 * tj) = h[rr + 1];
        }
    }

#pragma unroll
    for (int m = 0; m < RPT; ++m) {
        float4 v = make_float4(acc[m][0], acc[m][1], acc[m][2], acc[m][3]);
        *reinterpret_cast<float4*>(dst + (size_t)(i0 + m) * WW + J0 + 4 * tj) = v;
    }
}

extern "C" void kernel_launch(void* const* d_in, const int* in_sizes, int n_in,
                              void* d_out, int out_size, void* d_ws, size_t ws_size,
                              hipStream_t stream) {
    const float* in  = (const float*)d_in[0];
    float*       out = (float*)d_out;
    const int B = in_sizes[0] / (HH * WW);   // 64
    dim3 block(64, WAVES, 1);
    dim3 grid(WW / 256, HH / (WAVES * RPT), B);
    hipLaunchKernelGGL(diamond_kernel, grid, block, 0, stream, in, out);
}

// Round 4
// 383.347 us; speedup vs baseline: 2.0245x; 2.0245x over previous
//
#include <hip/hip_runtime.h>

#define HH 1024
#define WW 1024
#define RPT 16           // output rows per thread
#define NR (RPT + 10)    // input rows streamed
#define WAVES 4

__global__ __launch_bounds__(256) void diamond_kernel(const float* __restrict__ in,
                                                      float* __restrict__ out) {
    const int tj = threadIdx.x;          // lane 0..63, owns cols j0..j0+3
    const int ty = threadIdx.y;          // wave 0..3
    const int b  = blockIdx.z;
    const int J0 = blockIdx.x * 256;
    const int i0 = blockIdx.y * (WAVES * RPT) + ty * RPT;
    const float* __restrict__ src = in  + (size_t)b * HH * WW;
    float*       __restrict__ dst = out + (size_t)b * HH * WW;

    const float EV[6] = {1.0f,
                         0.36787944117144233f,   // e^-1
                         0.1353352832366127f,    // e^-2
                         0.049787068367863944f,  // e^-3
                         0.018315638888734179f,  // e^-4
                         0.006737946999085467f}; // e^-5

    float acc[RPT][4];
#pragma unroll
    for (int m = 0; m < RPT; ++m)
#pragma unroll
        for (int p = 0; p < 4; ++p) acc[m][p] = 0.0f;

    const int  cb_own = J0 + 4 * tj;
    const bool eL  = (tj < 2);           // need chunk tj-2 .w from global
    const bool eL0 = (tj == 0);          // need chunk tj-1 full from global
    const bool eR  = (tj >= 62);         // need chunk tj+2 .x from global
    const bool eR1 = (tj == 63);         // need chunk tj+1 full from global
    const int cb_hA = (J0 - 8 + 4 * tj) & (WW - 1);          // lanes 0,1
    const int cb_hL = (J0 - 4) & (WW - 1);                   // lane 0
    const int cb_hC = (J0 + 256 + 4 * (tj - 62)) & (WW - 1); // lanes 62,63
    const int cb_hR = (J0 + 256) & (WW - 1);                 // lane 63

    // two named prefetch slots, selected by compile-time (rr&1) after unroll
    float4 c2[2], hL2[2], hR2[2];
    float  wA2[2], xC2[2];

#define LOADROW(rr, sl) do {                                                   \
        const float* row_ = src + (size_t)((i0 + (rr) - 5) & (HH - 1)) * WW;   \
        c2[sl] = *reinterpret_cast<const float4*>(row_ + cb_own);              \
        if (eL)  { float4 t_ = *reinterpret_cast<const float4*>(row_ + cb_hA); \
                   wA2[sl] = t_.w; }                                           \
        if (eL0) hL2[sl] = *reinterpret_cast<const float4*>(row_ + cb_hL);     \
        if (eR)  { float4 t_ = *reinterpret_cast<const float4*>(row_ + cb_hC); \
                   xC2[sl] = t_.x; }                                           \
        if (eR1) hR2[sl] = *reinterpret_cast<const float4*>(row_ + cb_hR);     \
    } while (0)

    LOADROW(0, 0);

#pragma unroll
    for (int rr = 0; rr < NR; ++rr) {
        const int sl = rr & 1;
        if (rr + 1 < NR) LOADROW(rr + 1, sl ^ 1);

        const float4 c = c2[sl];

        // halo via cross-lane shuffle (wave covers 256 contiguous columns)
        float4 cL1, cR1;
        const int lm1 = (tj + 63) & 63, lp1 = (tj + 1) & 63;
        cL1.x = __shfl(c.x, lm1, 64);
        cL1.y = __shfl(c.y, lm1, 64);
        cL1.z = __shfl(c.z, lm1, 64);
        cL1.w = __shfl(c.w, lm1, 64);
        cR1.x = __shfl(c.x, lp1, 64);
        cR1.y = __shfl(c.y, lp1, 64);
        cR1.z = __shfl(c.z, lp1, 64);
        cR1.w = __shfl(c.w, lp1, 64);
        float cL2w = __shfl(c.w, (tj + 62) & 63, 64);
        float cR2x = __shfl(c.x, (tj + 2) & 63, 64);
        if (eL0) cL1  = hL2[sl];
        if (eR1) cR1  = hR2[sl];
        if (eL)  cL2w = wA2[sl];
        if (eR)  cR2x = xC2[sl];

        // window s[3..16] = cols j0-5 .. j0+8
        float s[17];
        s[3]  = cL2w;
        s[4]  = cL1.x; s[5]  = cL1.y; s[6]  = cL1.z; s[7]  = cL1.w;
        s[8]  = c.x;   s[9]  = c.y;   s[10] = c.z;   s[11] = c.w;
        s[12] = cR1.x; s[13] = cR1.y; s[14] = cR1.z; s[15] = cR1.w;
        s[16] = cR2x;

        // level-k sums consumed on the fly:
        // level k feeds output rows m = rr-k and m = rr-10+k with weight EV[5-k]
        float Hc[4];
#pragma unroll
        for (int p = 0; p < 4; ++p) Hc[p] = s[8 + p];
        {   // k = 0, a = 5
            const int m1 = rr - 10, m2 = rr;
            if (m1 >= 0 && m1 < RPT)
#pragma unroll
                for (int p = 0; p < 4; ++p) acc[m1][p] = fmaf(EV[5], Hc[p], acc[m1][p]);
            if (m2 >= 0 && m2 < RPT)
#pragma unroll
                for (int p = 0; p < 4; ++p) acc[m2][p] = fmaf(EV[5], Hc[p], acc[m2][p]);
        }
#pragma unroll
        for (int k = 1; k <= 4; ++k) {
#pragma unroll
            for (int p = 0; p < 4; ++p)
                Hc[p] = fmaf(EV[k], s[8 + p - k] + s[8 + p + k], Hc[p]);
            const int a = 5 - k;
            const int m1 = rr - 10 + k, m2 = rr - k;
            if (m1 >= 0 && m1 < RPT)
#pragma unroll
                for (int p = 0; p < 4; ++p) acc[m1][p] = fmaf(EV[a], Hc[p], acc[m1][p]);
            if (m2 >= 0 && m2 < RPT && m2 != m1)
#pragma unroll
                for (int p = 0; p < 4; ++p) acc[m2][p] = fmaf(EV[a], Hc[p], acc[m2][p]);
        }
        {   // k = 5 → center row (a = 0): weight 1, subtract self term
#pragma unroll
            for (int p = 0; p < 4; ++p)
                Hc[p] = fmaf(EV[5], s[8 + p - 5] + s[8 + p + 5], Hc[p]);
            const int m = rr - 5;
            if (m >= 0 && m < RPT)
#pragma unroll
                for (int p = 0; p < 4; ++p) acc[m][p] += Hc[p] - s[8 + p];
        }
    }
#undef LOADROW

#pragma unroll
    for (int m = 0; m < RPT; ++m) {
        float4 v = make_float4(acc[m][0], acc[m][1], acc[m][2], acc[m][3]);
        *reinterpret_cast<float4*>(dst + (size_t)(i0 + m) * WW + cb_own) = v;
    }
}

extern "C" void kernel_launch(void* const* d_in, const int* in_sizes, int n_in,
                              void* d_out, int out_size, void* d_ws, size_t ws_size,
                              hipStream_t stream) {
    const float* in  = (const float*)d_in[0];
    float*       out = (float*)d_out;
    const int B = in_sizes[0] / (HH * WW);   // 64
    dim3 block(64, WAVES, 1);
    dim3 grid(WW / 256, HH / (WAVES * RPT), B);
    hipLaunchKernelGGL(diamond_kernel, grid, block, 0, stream, in, out);
}